// Round 1
// 699.209 us; speedup vs baseline: 1.0487x; 1.0487x over previous
//
#include <hip/hip_runtime.h>

// Problem constants (fixed by setup_inputs): im0 [B,C,H,W] fp32,
// flow [B,H,W,2] fp32, out [B,C,H,W] fp32.
constexpr int B_ = 4;
constexpr int C_ = 3;
constexpr int H_ = 1024;
constexpr int W_ = 1920;
constexpr int HW_ = H_ * W_;

// Gather formulation: each block OWNS a TW x TH output tile (all 3 channels
// in LDS at once: 3*4096*4 = 48 KB -> 3 blocks/CU -> 24 waves/CU).
// It scans the (TW+2R)x(TH+2R) source region and accumulates, via LDS
// atomics, exactly those splat corners that (a) land inside its tile and
// (b) have displacement <= R in both axes. Output is then written with
// plain coalesced float4 stores -- no global atomics, no output memset.
// Corners with displacement > R (P ~ 0.5% of pixels for flow~N(0,5)) are
// handled exactly once by the second kernel (stream-ordered after the
// stores), which rescans flow, quick-rejects near pixels, and atomically
// adds the survivors. The two conditions partition all valid splats.
constexpr int TW = 64;
constexpr int TH = 64;
constexpr int R  = 16;
constexpr int EW = TW + 2 * R;      // 96
constexpr int EH = TH + 2 * R;      // 96
constexpr int TCELLS = TW * TH;     // 4096
constexpr int NTHR = 512;

static_assert(W_ % TW == 0 && H_ % TH == 0, "exact tiling assumed");

__global__ __launch_bounds__(NTHR, 6) void fw_gather(
    const float* __restrict__ im0,
    const float2* __restrict__ flow,
    const int* __restrict__ mode_p,
    float* __restrict__ out) {
    __shared__ float tile[C_][TCELLS];

    const int tx0 = blockIdx.x * TW;
    const int ty0 = blockIdx.y * TH;
    const int b   = blockIdx.z;
    const int mode = *mode_p;                  // wave-uniform

    float* t0 = &tile[0][0];
    for (int i = threadIdx.x; i < C_ * TCELLS; i += NTHR) t0[i] = 0.0f;
    __syncthreads();

    const float*  im0b  = im0  + (size_t)b * C_ * HW_;
    const float2* flowb = flow + (size_t)b * HW_;

    for (int p = threadIdx.x; p < EW * EH; p += NTHR) {
        const int ly = p / EW;                 // magic-mul div, cheap
        const int lx = p - ly * EW;
        const int gx = tx0 - R + lx;
        const int gy = ty0 - R + ly;
        if ((unsigned)gx >= (unsigned)W_ || (unsigned)gy >= (unsigned)H_)
            continue;                          // image-border halo clip

        const float2 f = flowb[gy * W_ + gx];
        const float px = (float)gx + f.x;
        const float py = (float)gy + f.y;

        if (mode == 1) {                       // nearest
            const int cx = (int)rintf(px);
            const int cy = (int)rintf(py);
            const int ltx = cx - tx0, lty = cy - ty0;
            const int dx = cx - gx, dy = cy - gy;
            if ((unsigned)ltx < (unsigned)TW && (unsigned)lty < (unsigned)TH &&
                dx >= -R && dx <= R && dy >= -R && dy <= R) {
                const int src = gy * W_ + gx;
                const int idx = lty * TW + ltx;
                atomicAdd(&tile[0][idx], im0b[src]);
                atomicAdd(&tile[1][idx], im0b[src + HW_]);
                atomicAdd(&tile[2][idx], im0b[src + 2 * HW_]);
            }
        } else {                               // bilinear, 4 corners
            const float xf = floorf(px), yf = floorf(py);
            const int x0 = (int)xf, y0 = (int)yf;
            const float wx1 = px - xf, wy1 = py - yf;
            const float wx0 = 1.0f - wx1, wy0 = 1.0f - wy1;

            const int   cxs[4] = { x0, x0 + 1, x0,     x0 + 1 };
            const int   cys[4] = { y0, y0,     y0 + 1, y0 + 1 };
            const float cws[4] = { wx0 * wy0, wx1 * wy0, wx0 * wy1, wx1 * wy1 };

            // Static unroll: masks/arrays stay in registers (no scratch).
            bool m[4];
            bool any = false;
#pragma unroll
            for (int k = 0; k < 4; ++k) {
                const int ltx = cxs[k] - tx0, lty = cys[k] - ty0;
                const int dx = cxs[k] - gx, dy = cys[k] - gy;
                m[k] = ((unsigned)ltx < (unsigned)TW) &&
                       ((unsigned)lty < (unsigned)TH) &&
                       (dx >= -R) && (dx <= R) && (dy >= -R) && (dy <= R);
                any = any || m[k];
            }
            if (!any) continue;                // halo source missing tile

            const int src = gy * W_ + gx;
            const float s0 = im0b[src];
            const float s1 = im0b[src + HW_];
            const float s2 = im0b[src + 2 * HW_];
#pragma unroll
            for (int k = 0; k < 4; ++k) {
                if (m[k]) {
                    const int idx = (cys[k] - ty0) * TW + (cxs[k] - tx0);
                    const float w = cws[k];
                    atomicAdd(&tile[0][idx], s0 * w);
                    atomicAdd(&tile[1][idx], s1 * w);
                    atomicAdd(&tile[2][idx], s2 * w);
                }
            }
        }
    }
    __syncthreads();

    // Dense, coalesced, NON-atomic float4 stores: each output pixel is
    // produced by exactly one block -> no memset, no global atomics.
    for (int i = threadIdx.x; i < C_ * (TCELLS / 4); i += NTHR) {
        const int c    = i >> 10;              // TCELLS/4 == 1024
        const int j    = i & 1023;
        const int row  = j >> 4;               // 16 float4 per 64-wide row
        const int col4 = j & 15;
        const float4 v = reinterpret_cast<const float4*>(&tile[c][0])[j];
        float* dst = out + ((size_t)(b * C_ + c)) * HW_ +
                     (size_t)(ty0 + row) * W_ + tx0 + col4 * 4;
        *reinterpret_cast<float4*>(dst) = v;
    }
}

// Second pass (stream-ordered after fw_gather): handle the rare corners
// with displacement > R. Exact complement of the gather condition.
__global__ __launch_bounds__(256) void fw_far(
    const float* __restrict__ im0,
    const float2* __restrict__ flow,
    const int* __restrict__ mode_p,
    float* __restrict__ out) {
    const int mode = *mode_p;
    const int total = B_ * HW_;
    const float lim = (float)(R - 1);          // safe reject bound (see note)
    for (int idx = blockIdx.x * 256 + threadIdx.x; idx < total;
         idx += gridDim.x * 256) {
        const float2 f = flow[idx];
        // |f.x|<R-1 -> bilinear corner disp in [-R, R-1], nearest in
        // [-(R-1), R-1]: guaranteed near, handled by gather. ~99.5% exit here.
        if (fabsf(f.x) < lim && fabsf(f.y) < lim) continue;

        const int b   = idx / HW_;
        const int rem = idx - b * HW_;
        const int gy  = rem / W_;
        const int gx  = rem - gy * W_;
        const float px = (float)gx + f.x;
        const float py = (float)gy + f.y;
        const float* im0b = im0 + (size_t)b * C_ * HW_;
        float*       outb = out + (size_t)b * C_ * HW_;
        const int src = gy * W_ + gx;

        if (mode == 1) {
            const int cx = (int)rintf(px);
            const int cy = (int)rintf(py);
            const int dx = cx - gx, dy = cy - gy;
            const bool in = (unsigned)cx < (unsigned)W_ &&
                            (unsigned)cy < (unsigned)H_;
            if (in && (dx < -R || dx > R || dy < -R || dy > R)) {
                const int dsti = cy * W_ + cx;
                unsafeAtomicAdd(outb + dsti,            im0b[src]);
                unsafeAtomicAdd(outb + HW_ + dsti,      im0b[src + HW_]);
                unsafeAtomicAdd(outb + 2 * HW_ + dsti,  im0b[src + 2 * HW_]);
            }
        } else {
            const float xf = floorf(px), yf = floorf(py);
            const int x0 = (int)xf, y0 = (int)yf;
            const float wx1 = px - xf, wy1 = py - yf;
            const float wx0 = 1.0f - wx1, wy0 = 1.0f - wy1;

            const int   cxs[4] = { x0, x0 + 1, x0,     x0 + 1 };
            const int   cys[4] = { y0, y0,     y0 + 1, y0 + 1 };
            const float cws[4] = { wx0 * wy0, wx1 * wy0, wx0 * wy1, wx1 * wy1 };

            bool m[4];
            bool any = false;
#pragma unroll
            for (int k = 0; k < 4; ++k) {
                const int dx = cxs[k] - gx, dy = cys[k] - gy;
                const bool in = (unsigned)cxs[k] < (unsigned)W_ &&
                                (unsigned)cys[k] < (unsigned)H_;
                m[k] = in && (dx < -R || dx > R || dy < -R || dy > R);
                any = any || m[k];
            }
            if (!any) continue;

            const float s0 = im0b[src];
            const float s1 = im0b[src + HW_];
            const float s2 = im0b[src + 2 * HW_];
#pragma unroll
            for (int k = 0; k < 4; ++k) {
                if (m[k]) {
                    const int dsti = cys[k] * W_ + cxs[k];
                    const float w = cws[k];
                    unsafeAtomicAdd(outb + dsti,           s0 * w);
                    unsafeAtomicAdd(outb + HW_ + dsti,     s1 * w);
                    unsafeAtomicAdd(outb + 2 * HW_ + dsti, s2 * w);
                }
            }
        }
    }
}

extern "C" void kernel_launch(void* const* d_in, const int* in_sizes, int n_in,
                              void* d_out, int out_size, void* d_ws, size_t ws_size,
                              hipStream_t stream) {
    const float*  im0  = (const float*)d_in[0];
    const float2* flow = (const float2*)d_in[1];
    // d_in[2] = flowback (unused by the forward splat)
    const int*    mode = (const int*)d_in[3];
    float* out = (float*)d_out;

    // No memset: fw_gather writes every output pixel exactly once with a
    // plain store; fw_far's atomics are stream-ordered after it.
    dim3 grid(W_ / TW, H_ / TH, B_);
    fw_gather<<<grid, dim3(NTHR), 0, stream>>>(im0, flow, mode, out);
    fw_far<<<dim3(2048), dim3(256), 0, stream>>>(im0, flow, mode, out);
}

// Round 2
// 695.852 us; speedup vs baseline: 1.0538x; 1.0048x over previous
//
#include <hip/hip_runtime.h>

// Problem constants (fixed by setup_inputs): im0 [B,C,H,W] fp32,
// flow [B,H,W,2] fp32, out [B,C,H,W] fp32.
constexpr int B_ = 4;
constexpr int C_ = 3;
constexpr int H_ = 1024;
constexpr int W_ = 1920;
constexpr int HW_ = H_ * W_;

// Gather formulation: each block OWNS a TW x TH output tile (all 3 channels
// in LDS at once: 3*4096*4 = 48 KB -> 3 blocks/CU -> 24 waves/CU).
// It scans the (TW+2R)x(TH+2R) source region and accumulates, via NATIVE
// LDS atomics (ds_add_f32 -- unsafeAtomicAdd; plain atomicAdd on shared
// f32 compiles to a safe-fp CAS retry loop, which was the 518us bottleneck),
// exactly those splat corners that (a) land inside its tile and (b) have
// displacement <= R in both axes. Output is then written with plain
// coalesced float4 stores -- no global atomics, no output memset.
// Corners with displacement > R are handled exactly once by fw_far
// (stream-ordered after the stores). The two conditions partition all
// valid splats.
constexpr int TW = 64;
constexpr int TH = 64;
constexpr int R  = 16;
constexpr int EW = TW + 2 * R;      // 96
constexpr int EH = TH + 2 * R;      // 96
constexpr int TCELLS = TW * TH;     // 4096
constexpr int NTHR = 512;

static_assert(W_ % TW == 0 && H_ % TH == 0, "exact tiling assumed");

__global__ __launch_bounds__(NTHR, 6) void fw_gather(
    const float* __restrict__ im0,
    const float2* __restrict__ flow,
    const int* __restrict__ mode_p,
    float* __restrict__ out) {
    __shared__ float tile[C_][TCELLS];

    const int tx0 = blockIdx.x * TW;
    const int ty0 = blockIdx.y * TH;
    const int b   = blockIdx.z;
    const int mode = *mode_p;                  // wave-uniform

    float* t0 = &tile[0][0];
    for (int i = threadIdx.x; i < C_ * TCELLS; i += NTHR) t0[i] = 0.0f;
    __syncthreads();

    const float*  im0b  = im0  + (size_t)b * C_ * HW_;
    const float2* flowb = flow + (size_t)b * HW_;

    for (int p = threadIdx.x; p < EW * EH; p += NTHR) {
        const int ly = p / EW;                 // magic-mul div, cheap
        const int lx = p - ly * EW;
        const int gx = tx0 - R + lx;
        const int gy = ty0 - R + ly;
        if ((unsigned)gx >= (unsigned)W_ || (unsigned)gy >= (unsigned)H_)
            continue;                          // image-border halo clip

        const float2 f = flowb[gy * W_ + gx];
        const float px = (float)gx + f.x;
        const float py = (float)gy + f.y;

        if (mode == 1) {                       // nearest
            const int cx = (int)rintf(px);
            const int cy = (int)rintf(py);
            const int ltx = cx - tx0, lty = cy - ty0;
            const int dx = cx - gx, dy = cy - gy;
            if ((unsigned)ltx < (unsigned)TW && (unsigned)lty < (unsigned)TH &&
                dx >= -R && dx <= R && dy >= -R && dy <= R) {
                const int src = gy * W_ + gx;
                const int idx = lty * TW + ltx;
                unsafeAtomicAdd(&tile[0][idx], im0b[src]);
                unsafeAtomicAdd(&tile[1][idx], im0b[src + HW_]);
                unsafeAtomicAdd(&tile[2][idx], im0b[src + 2 * HW_]);
            }
        } else {                               // bilinear, 4 corners
            const float xf = floorf(px), yf = floorf(py);
            const int x0 = (int)xf, y0 = (int)yf;
            const float wx1 = px - xf, wy1 = py - yf;
            const float wx0 = 1.0f - wx1, wy0 = 1.0f - wy1;

            const int   cxs[4] = { x0, x0 + 1, x0,     x0 + 1 };
            const int   cys[4] = { y0, y0,     y0 + 1, y0 + 1 };
            const float cws[4] = { wx0 * wy0, wx1 * wy0, wx0 * wy1, wx1 * wy1 };

            // Static unroll: masks/arrays stay in registers (no scratch).
            bool m[4];
            bool any = false;
#pragma unroll
            for (int k = 0; k < 4; ++k) {
                const int ltx = cxs[k] - tx0, lty = cys[k] - ty0;
                const int dx = cxs[k] - gx, dy = cys[k] - gy;
                m[k] = ((unsigned)ltx < (unsigned)TW) &&
                       ((unsigned)lty < (unsigned)TH) &&
                       (dx >= -R) && (dx <= R) && (dy >= -R) && (dy <= R);
                any = any || m[k];
            }
            if (!any) continue;                // halo source missing tile

            const int src = gy * W_ + gx;
            const float s0 = im0b[src];
            const float s1 = im0b[src + HW_];
            const float s2 = im0b[src + 2 * HW_];
#pragma unroll
            for (int k = 0; k < 4; ++k) {
                if (m[k]) {
                    const int idx = (cys[k] - ty0) * TW + (cxs[k] - tx0);
                    const float w = cws[k];
                    unsafeAtomicAdd(&tile[0][idx], s0 * w);
                    unsafeAtomicAdd(&tile[1][idx], s1 * w);
                    unsafeAtomicAdd(&tile[2][idx], s2 * w);
                }
            }
        }
    }
    __syncthreads();

    // Dense, coalesced, NON-atomic float4 stores: each output pixel is
    // produced by exactly one block -> no memset, no global atomics.
    for (int i = threadIdx.x; i < C_ * (TCELLS / 4); i += NTHR) {
        const int c    = i >> 10;              // TCELLS/4 == 1024
        const int j    = i & 1023;
        const int row  = j >> 4;               // 16 float4 per 64-wide row
        const int col4 = j & 15;
        const float4 v = reinterpret_cast<const float4*>(&tile[c][0])[j];
        float* dst = out + ((size_t)(b * C_ + c)) * HW_ +
                     (size_t)(ty0 + row) * W_ + tx0 + col4 * 4;
        *reinterpret_cast<float4*>(dst) = v;
    }
}

// Second pass (stream-ordered after fw_gather): handle the rare corners
// with displacement > R. Exact complement of the gather condition.
// Flat 1-pixel-per-thread launch: the previous 15-deep grid-stride loop
// serialized a ~dozen dependent load latencies per thread (181 us for a
// 63 MB scan); flat gives maximal TLP on the 99.5% load->test->exit path.
__global__ __launch_bounds__(256) void fw_far(
    const float* __restrict__ im0,
    const float2* __restrict__ flow,
    const int* __restrict__ mode_p,
    float* __restrict__ out) {
    const int idx = blockIdx.x * 256 + threadIdx.x;
    if (idx >= B_ * HW_) return;

    const float2 f = flow[idx];
    // |f.x|<R-1 -> bilinear corner disp in [-R, R-1], nearest in
    // [-(R-1), R-1]: guaranteed near, handled by gather. ~99.5% exit here.
    const float lim = (float)(R - 1);
    if (fabsf(f.x) < lim && fabsf(f.y) < lim) return;

    const int mode = *mode_p;
    const int b   = idx / HW_;
    const int rem = idx - b * HW_;
    const int gy  = rem / W_;
    const int gx  = rem - gy * W_;
    const float px = (float)gx + f.x;
    const float py = (float)gy + f.y;
    const float* im0b = im0 + (size_t)b * C_ * HW_;
    float*       outb = out + (size_t)b * C_ * HW_;
    const int src = gy * W_ + gx;

    if (mode == 1) {
        const int cx = (int)rintf(px);
        const int cy = (int)rintf(py);
        const int dx = cx - gx, dy = cy - gy;
        const bool in = (unsigned)cx < (unsigned)W_ &&
                        (unsigned)cy < (unsigned)H_;
        if (in && (dx < -R || dx > R || dy < -R || dy > R)) {
            const int dsti = cy * W_ + cx;
            unsafeAtomicAdd(outb + dsti,            im0b[src]);
            unsafeAtomicAdd(outb + HW_ + dsti,      im0b[src + HW_]);
            unsafeAtomicAdd(outb + 2 * HW_ + dsti,  im0b[src + 2 * HW_]);
        }
    } else {
        const float xf = floorf(px), yf = floorf(py);
        const int x0 = (int)xf, y0 = (int)yf;
        const float wx1 = px - xf, wy1 = py - yf;
        const float wx0 = 1.0f - wx1, wy0 = 1.0f - wy1;

        const int   cxs[4] = { x0, x0 + 1, x0,     x0 + 1 };
        const int   cys[4] = { y0, y0,     y0 + 1, y0 + 1 };
        const float cws[4] = { wx0 * wy0, wx1 * wy0, wx0 * wy1, wx1 * wy1 };

        bool m[4];
        bool any = false;
#pragma unroll
        for (int k = 0; k < 4; ++k) {
            const int dx = cxs[k] - gx, dy = cys[k] - gy;
            const bool in = (unsigned)cxs[k] < (unsigned)W_ &&
                            (unsigned)cys[k] < (unsigned)H_;
            m[k] = in && (dx < -R || dx > R || dy < -R || dy > R);
            any = any || m[k];
        }
        if (!any) return;

        const float s0 = im0b[src];
        const float s1 = im0b[src + HW_];
        const float s2 = im0b[src + 2 * HW_];
#pragma unroll
        for (int k = 0; k < 4; ++k) {
            if (m[k]) {
                const int dsti = cys[k] * W_ + cxs[k];
                const float w = cws[k];
                unsafeAtomicAdd(outb + dsti,           s0 * w);
                unsafeAtomicAdd(outb + HW_ + dsti,     s1 * w);
                unsafeAtomicAdd(outb + 2 * HW_ + dsti, s2 * w);
            }
        }
    }
}

extern "C" void kernel_launch(void* const* d_in, const int* in_sizes, int n_in,
                              void* d_out, int out_size, void* d_ws, size_t ws_size,
                              hipStream_t stream) {
    const float*  im0  = (const float*)d_in[0];
    const float2* flow = (const float2*)d_in[1];
    // d_in[2] = flowback (unused by the forward splat)
    const int*    mode = (const int*)d_in[3];
    float* out = (float*)d_out;

    // No memset: fw_gather writes every output pixel exactly once with a
    // plain store; fw_far's atomics are stream-ordered after it.
    dim3 grid(W_ / TW, H_ / TH, B_);
    fw_gather<<<grid, dim3(NTHR), 0, stream>>>(im0, flow, mode, out);

    constexpr int total = B_ * HW_;
    fw_far<<<dim3((total + 255) / 256), dim3(256), 0, stream>>>(im0, flow, mode, out);
}

// Round 3
// 694.752 us; speedup vs baseline: 1.0554x; 1.0016x over previous
//
#include <hip/hip_runtime.h>

// Problem constants (fixed by setup_inputs): im0 [B,C,H,W] fp32,
// flow [B,H,W,2] fp32, out [B,C,H,W] fp32.
constexpr int B_ = 4;
constexpr int C_ = 3;
constexpr int H_ = 1024;
constexpr int W_ = 1920;
constexpr int HW_ = H_ * W_;

// Gather formulation: each block OWNS a TW x TH output tile (all 3 channels
// in LDS: 3*4096*4 = 48 KB -> 3 blocks/CU). It scans the (TW+2R)x(TH+2R)
// source halo and accumulates via ds_add_f32 exactly those splat corners
// that (a) land inside its tile and (b) have displacement <= R. Output is
// written with plain coalesced float4 stores. Far corners (|disp|>R) are
// handled once by fw_far. The two conditions partition all valid splats.
//
// R3 restructure: the splat loop processes 4-pixel QUADS with all loads
// hoisted and vectorized (2x float4 flow + 3x float4 im0, issued together
// -> one vmcnt wait per quad instead of two serial waits per pixel). Quads
// are 4-aligned and W%4==0, so every quad is entirely inside or outside
// the image: no misaligned loads, no per-pixel OOB branches. This tests
// the latency-convoy theory; atomic count is unchanged (theory A control).
constexpr int TW = 64;
constexpr int TH = 64;
constexpr int R  = 16;
constexpr int EW = TW + 2 * R;      // 96
constexpr int EH = TH + 2 * R;      // 96
constexpr int TCELLS = TW * TH;     // 4096
constexpr int NTHR = 512;
constexpr int QPR = EW / 4;         // 24 quads per halo row
constexpr int NQ  = QPR * EH;       // 2304 quads

static_assert(W_ % TW == 0 && H_ % TH == 0, "exact tiling assumed");
static_assert(W_ % 4 == 0 && EW % 4 == 0, "quad alignment assumed");

__global__ __launch_bounds__(NTHR, 6) void fw_gather(
    const float* __restrict__ im0,
    const float2* __restrict__ flow,
    const int* __restrict__ mode_p,
    float* __restrict__ out) {
    __shared__ float tile[C_][TCELLS];

    const int tx0 = blockIdx.x * TW;
    const int ty0 = blockIdx.y * TH;
    const int b   = blockIdx.z;
    const int mode = *mode_p;                  // wave-uniform

    float* t0 = &tile[0][0];
    for (int i = threadIdx.x; i < C_ * TCELLS; i += NTHR) t0[i] = 0.0f;
    __syncthreads();

    const float*  im0b  = im0  + (size_t)b * C_ * HW_;
    const float2* flowb = flow + (size_t)b * HW_;

    for (int q = threadIdx.x; q < NQ; q += NTHR) {
        const int qy = q / QPR;                // magic-mul div
        const int qx = (q - qy * QPR) * 4;
        const int gy = ty0 - R + qy;
        const int gx = tx0 - R + qx;
        // Quads are 4-aligned; image width is a multiple of 4 -> a quad is
        // entirely in-image iff its first pixel is. Whole-quad reject:
        if ((unsigned)gy >= (unsigned)H_) continue;
        if ((unsigned)gx >= (unsigned)W_) continue;

        const int src = gy * W_ + gx;          // multiple of 4
        // Independent wide loads, all issued before any use:
        const float4 f01 = reinterpret_cast<const float4*>(flowb)[src >> 1];
        const float4 f23 = reinterpret_cast<const float4*>(flowb)[(src >> 1) + 1];
        const float4 sA  = reinterpret_cast<const float4*>(im0b)[src >> 2];
        const float4 sB  = reinterpret_cast<const float4*>(im0b + HW_)[src >> 2];
        const float4 sC  = reinterpret_cast<const float4*>(im0b + 2 * HW_)[src >> 2];

        const float fx[4] = { f01.x, f01.z, f23.x, f23.z };
        const float fy[4] = { f01.y, f01.w, f23.y, f23.w };
        const float s0[4] = { sA.x, sA.y, sA.z, sA.w };
        const float s1[4] = { sB.x, sB.y, sB.z, sB.w };
        const float s2[4] = { sC.x, sC.y, sC.z, sC.w };

        if (mode == 1) {                       // nearest
#pragma unroll
            for (int i = 0; i < 4; ++i) {
                const int gxi = gx + i;
                const int cx = (int)rintf((float)gxi + fx[i]);
                const int cy = (int)rintf((float)gy  + fy[i]);
                const int ltx = cx - tx0, lty = cy - ty0;
                const int dx = cx - gxi, dy = cy - gy;
                if ((unsigned)ltx < (unsigned)TW && (unsigned)lty < (unsigned)TH &&
                    dx >= -R && dx <= R && dy >= -R && dy <= R) {
                    const int idx = lty * TW + ltx;
                    unsafeAtomicAdd(&tile[0][idx], s0[i]);
                    unsafeAtomicAdd(&tile[1][idx], s1[i]);
                    unsafeAtomicAdd(&tile[2][idx], s2[i]);
                }
            }
        } else {                               // bilinear, 4 corners
#pragma unroll
            for (int i = 0; i < 4; ++i) {
                const int gxi = gx + i;
                const float px = (float)gxi + fx[i];
                const float py = (float)gy  + fy[i];
                const float xf = floorf(px), yf = floorf(py);
                const int x0 = (int)xf, y0 = (int)yf;
                const float wx1 = px - xf, wy1 = py - yf;
                const float wx0 = 1.0f - wx1, wy0 = 1.0f - wy1;

                const int lx0 = x0 - tx0, ly0 = y0 - ty0;
                const int dx0 = x0 - gxi, dy0 = y0 - gy;
                // per-axis validity (corner x in {x0,x0+1}, y in {y0,y0+1})
                const bool vx0 = ((unsigned)lx0 < (unsigned)TW) &&
                                 (dx0 >= -R) && (dx0 <= R);
                const bool vx1 = ((unsigned)(lx0 + 1) < (unsigned)TW) &&
                                 (dx0 + 1 >= -R) && (dx0 + 1 <= R);
                const bool vy0 = ((unsigned)ly0 < (unsigned)TH) &&
                                 (dy0 >= -R) && (dy0 <= R);
                const bool vy1 = ((unsigned)(ly0 + 1) < (unsigned)TH) &&
                                 (dy0 + 1 >= -R) && (dy0 + 1 <= R);
                if (!((vx0 || vx1) && (vy0 || vy1))) continue;

                const int idx00 = ly0 * TW + lx0;
                if (vy0) {
                    if (vx0) {
                        const float w = wx0 * wy0;
                        unsafeAtomicAdd(&tile[0][idx00], s0[i] * w);
                        unsafeAtomicAdd(&tile[1][idx00], s1[i] * w);
                        unsafeAtomicAdd(&tile[2][idx00], s2[i] * w);
                    }
                    if (vx1) {
                        const float w = wx1 * wy0;
                        unsafeAtomicAdd(&tile[0][idx00 + 1], s0[i] * w);
                        unsafeAtomicAdd(&tile[1][idx00 + 1], s1[i] * w);
                        unsafeAtomicAdd(&tile[2][idx00 + 1], s2[i] * w);
                    }
                }
                if (vy1) {
                    if (vx0) {
                        const float w = wx0 * wy1;
                        unsafeAtomicAdd(&tile[0][idx00 + TW], s0[i] * w);
                        unsafeAtomicAdd(&tile[1][idx00 + TW], s1[i] * w);
                        unsafeAtomicAdd(&tile[2][idx00 + TW], s2[i] * w);
                    }
                    if (vx1) {
                        const float w = wx1 * wy1;
                        unsafeAtomicAdd(&tile[0][idx00 + TW + 1], s0[i] * w);
                        unsafeAtomicAdd(&tile[1][idx00 + TW + 1], s1[i] * w);
                        unsafeAtomicAdd(&tile[2][idx00 + TW + 1], s2[i] * w);
                    }
                }
            }
        }
    }
    __syncthreads();

    // Dense, coalesced, NON-atomic float4 stores: each output pixel is
    // produced by exactly one block -> no memset, no global atomics.
    for (int i = threadIdx.x; i < C_ * (TCELLS / 4); i += NTHR) {
        const int c    = i >> 10;              // TCELLS/4 == 1024
        const int j    = i & 1023;
        const int row  = j >> 4;               // 16 float4 per 64-wide row
        const int col4 = j & 15;
        const float4 v = reinterpret_cast<const float4*>(&tile[c][0])[j];
        float* dst = out + ((size_t)(b * C_ + c)) * HW_ +
                     (size_t)(ty0 + row) * W_ + tx0 + col4 * 4;
        *reinterpret_cast<float4*>(dst) = v;
    }
}

// Second pass (stream-ordered after fw_gather): handle the rare corners
// with displacement > R. Exact complement of the gather condition.
__global__ __launch_bounds__(256) void fw_far(
    const float* __restrict__ im0,
    const float2* __restrict__ flow,
    const int* __restrict__ mode_p,
    float* __restrict__ out) {
    const int idx = blockIdx.x * 256 + threadIdx.x;
    if (idx >= B_ * HW_) return;

    const float2 f = flow[idx];
    // |f.x|<R-1 -> bilinear corner disp in [-R, R-1], nearest in
    // [-(R-1), R-1]: guaranteed near, handled by gather. ~99.5% exit here.
    const float lim = (float)(R - 1);
    if (fabsf(f.x) < lim && fabsf(f.y) < lim) return;

    const int mode = *mode_p;
    const int b   = idx / HW_;
    const int rem = idx - b * HW_;
    const int gy  = rem / W_;
    const int gx  = rem - gy * W_;
    const float px = (float)gx + f.x;
    const float py = (float)gy + f.y;
    const float* im0b = im0 + (size_t)b * C_ * HW_;
    float*       outb = out + (size_t)b * C_ * HW_;
    const int src = gy * W_ + gx;

    if (mode == 1) {
        const int cx = (int)rintf(px);
        const int cy = (int)rintf(py);
        const int dx = cx - gx, dy = cy - gy;
        const bool in = (unsigned)cx < (unsigned)W_ &&
                        (unsigned)cy < (unsigned)H_;
        if (in && (dx < -R || dx > R || dy < -R || dy > R)) {
            const int dsti = cy * W_ + cx;
            unsafeAtomicAdd(outb + dsti,            im0b[src]);
            unsafeAtomicAdd(outb + HW_ + dsti,      im0b[src + HW_]);
            unsafeAtomicAdd(outb + 2 * HW_ + dsti,  im0b[src + 2 * HW_]);
        }
    } else {
        const float xf = floorf(px), yf = floorf(py);
        const int x0 = (int)xf, y0 = (int)yf;
        const float wx1 = px - xf, wy1 = py - yf;
        const float wx0 = 1.0f - wx1, wy0 = 1.0f - wy1;

        const int   cxs[4] = { x0, x0 + 1, x0,     x0 + 1 };
        const int   cys[4] = { y0, y0,     y0 + 1, y0 + 1 };
        const float cws[4] = { wx0 * wy0, wx1 * wy0, wx0 * wy1, wx1 * wy1 };

        bool m[4];
        bool any = false;
#pragma unroll
        for (int k = 0; k < 4; ++k) {
            const int dx = cxs[k] - gx, dy = cys[k] - gy;
            const bool in = (unsigned)cxs[k] < (unsigned)W_ &&
                            (unsigned)cys[k] < (unsigned)H_;
            m[k] = in && (dx < -R || dx > R || dy < -R || dy > R);
            any = any || m[k];
        }
        if (!any) return;

        const float s0 = im0b[src];
        const float s1 = im0b[src + HW_];
        const float s2 = im0b[src + 2 * HW_];
#pragma unroll
        for (int k = 0; k < 4; ++k) {
            if (m[k]) {
                const int dsti = cys[k] * W_ + cxs[k];
                const float w = cws[k];
                unsafeAtomicAdd(outb + dsti,           s0 * w);
                unsafeAtomicAdd(outb + HW_ + dsti,     s1 * w);
                unsafeAtomicAdd(outb + 2 * HW_ + dsti, s2 * w);
            }
        }
    }
}

extern "C" void kernel_launch(void* const* d_in, const int* in_sizes, int n_in,
                              void* d_out, int out_size, void* d_ws, size_t ws_size,
                              hipStream_t stream) {
    const float*  im0  = (const float*)d_in[0];
    const float2* flow = (const float2*)d_in[1];
    // d_in[2] = flowback (unused by the forward splat)
    const int*    mode = (const int*)d_in[3];
    float* out = (float*)d_out;

    // No memset: fw_gather writes every output pixel exactly once with a
    // plain store; fw_far's atomics are stream-ordered after it.
    dim3 grid(W_ / TW, H_ / TH, B_);
    fw_gather<<<grid, dim3(NTHR), 0, stream>>>(im0, flow, mode, out);

    constexpr int total = B_ * HW_;
    fw_far<<<dim3((total + 255) / 256), dim3(256), 0, stream>>>(im0, flow, mode, out);
}